// Round 2
// baseline (6909.343 us; speedup 1.0000x reference)
//
#include <hip/hip_runtime.h>
#include <hip/hip_bf16.h>

// Problem dims (fixed)
#define NB 1024   // batch
#define NI 256    // input size
#define NH 256    // hidden
#define NT 64     // window T
#define TM1 63    // T-1 steps

#define GRID_BLOCKS 256
#define BLOCK_THREADS 1024

typedef short bf16x8 __attribute__((ext_vector_type(8)));
typedef float f32x4 __attribute__((ext_vector_type(4)));

__device__ __forceinline__ float bf16s_to_f(short s){
    unsigned u = ((unsigned)(unsigned short)s) << 16;
    return __builtin_bit_cast(float, u);
}
__device__ __forceinline__ unsigned short f_to_bf16s(float f){
    __hip_bfloat16 h = __float2bfloat16(f);
    return *(unsigned short*)&h;
}
__device__ __forceinline__ unsigned pack_bf16(float lo, float hi){
    return (unsigned)f_to_bf16s(lo) | ((unsigned)f_to_bf16s(hi) << 16);
}

__device__ __forceinline__ float fast_exp2(float x){ return __builtin_amdgcn_exp2f(x); }
__device__ __forceinline__ float fast_rcp(float x){ return __builtin_amdgcn_rcpf(x); }
__device__ __forceinline__ float fast_tanh(float x){
    float e = fast_exp2(x * 2.8853900817779268f);   // 2*log2(e)
    return 1.f - 2.f * fast_rcp(e + 1.f);
}
__device__ __forceinline__ float fast_sigmoid(float x){
    return fast_rcp(1.f + fast_exp2(-1.4426950408889634f * x));
}

// ---------------------------------------------------------------------------
// Grid-wide barrier: per-block arrive slots + block-0 release broadcast.
// Device-scope atomics; one agent fence (wbl2/inv sc1) per block per side.
// Requires co-resident grid -> launched via hipLaunchCooperativeKernel.
// ---------------------------------------------------------------------------
__device__ __forceinline__ void gridbar(int* arrive, int* release_, int gen){
    __syncthreads();                       // all waves' stores drained to L2
    int tid = threadIdx.x;
    if (tid == 0){
        __threadfence();                   // flush this XCD's L2 to coherence point
        __hip_atomic_store(&arrive[blockIdx.x], gen,
                           __ATOMIC_RELEASE, __HIP_MEMORY_SCOPE_AGENT);
    }
    if (blockIdx.x == 0){
        if (tid < GRID_BLOCKS){
            while (__hip_atomic_load(&arrive[tid],
                     __ATOMIC_ACQUIRE, __HIP_MEMORY_SCOPE_AGENT) < gen) {}
        }
        __syncthreads();
        if (tid == 0)
            __hip_atomic_store(release_, gen,
                               __ATOMIC_RELEASE, __HIP_MEMORY_SCOPE_AGENT);
    }
    if (tid == 0){
        while (__hip_atomic_load(release_,
                 __ATOMIC_ACQUIRE, __HIP_MEMORY_SCOPE_AGENT) < gen) {}
        __threadfence();                   // invalidate L1/L2 before reads
    }
    __syncthreads();
}

// ---------------------------------------------------------------------------
// One-time prep (unchanged).
// ---------------------------------------------------------------------------
__global__ __launch_bounds__(256) void prep_w2(
    const float* __restrict__ Wih, const float* __restrict__ Whh,
    const float* __restrict__ bih, const float* __restrict__ bhh,
    const float* __restrict__ Wh,
    __hip_bfloat16* __restrict__ W2, float* __restrict__ bias,
    __hip_bfloat16* __restrict__ Wh3)
{
    int tid = threadIdx.x;
    if (blockIdx.x < 1024){
        int n = blockIdx.x;
        W2[(long)n*512 + tid]       = __float2bfloat16(Wih[(long)n*256 + tid]);
        W2[(long)n*512 + 256 + tid] = __float2bfloat16(Whh[(long)n*256 + tid]);
        if (tid == 0) bias[n] = bih[n] + bhh[n];
    } else {
        int idx = (blockIdx.x - 1024) * 256 + tid;   // 0..32767
        int k  = idx & 31;
        int u  = (idx >> 5) & 63;
        int jt = idx >> 11;
        float v = (k < 16) ? Wh[(jt*16 + k)*NT + u]
                           : Wh[(256 + jt*16 + (k - 16))*NT + u];
        Wh3[idx] = __float2bfloat16(v);   // layout ((jt*64)+u)*32+k == idx
    }
}

// ---------------------------------------------------------------------------
// prefsT[b][i][u] = b_fs[u] + sum_t FS[b][t][i]*W_fs[t][u]   (bf16, u-contig)
// (round-1 restructured version, unchanged)
// ---------------------------------------------------------------------------
__global__ __launch_bounds__(256) void prefs_kernel(
    const float* __restrict__ FS,    // [B][63][I] f32
    const float* __restrict__ Wfs,   // [64][64]   f32
    const float* __restrict__ bfs,   // [64]       f32
    __hip_bfloat16* __restrict__ prefsT)  // [B][I][64] bf16
{
    __shared__ float wfs_s[TM1][NT];
    int b = blockIdx.x, tid = threadIdx.x;
    for (int idx = tid; idx < TM1*NT; idx += 256)
        wfs_s[idx >> 6][idx & 63] = Wfs[idx];
    __syncthreads();

    const float* fsp = FS + (long)b*TM1*NI + tid;

    f32x4 acc[16];
    #pragma unroll
    for (int g = 0; g < 16; ++g) acc[g] = *(const f32x4*)(bfs + g*4);

    #pragma unroll 4
    for (int t = 0; t < TM1; ++t){
        float fs = fsp[(long)t*NI];
        #pragma unroll
        for (int g = 0; g < 16; ++g){
            f32x4 w4 = *(const f32x4*)&wfs_s[t][g*4];
            acc[g] += fs * w4;
        }
    }

    uint4* dst = (uint4*)(prefsT + ((long)b*NI + tid)*NT);
    #pragma unroll
    for (int g = 0; g < 16; g += 2){
        uint4 v;
        v.x = pack_bf16(acc[g][0],   acc[g][1]);
        v.y = pack_bf16(acc[g][2],   acc[g][3]);
        v.z = pack_bf16(acc[g+1][0], acc[g+1][1]);
        v.w = pack_bf16(acc[g+1][2], acc[g+1][3]);
        dst[g >> 1] = v;
    }
}

// ---------------------------------------------------------------------------
// Persistent kernel: all 63 steps, 2 grid barriers per step.
// 256 blocks x 1024 threads, 1 block/CU (co-resident via cooperative launch).
// Phase A: 4 batches/block (group g = tid>>8 handles batch blk*4+g).
// Phase B: block (mt=blk>>4, jt=blk&15): 64 batches x 16 j x 4 quadrants;
//          16 waves, each one 16x16 K=512 MFMA chain + LDS quadrant exchange
//          + 1-MFMA s2part mini-GEMM.
// ---------------------------------------------------------------------------
__global__ __launch_bounds__(BLOCK_THREADS, 4) void persist_kernel(
    const float* __restrict__ FS,
    const float* __restrict__ yhist,
    const float* __restrict__ bh,
    const float* __restrict__ Wfs,
    const float* __restrict__ Wattn,
    const float* __restrict__ battn,
    const __hip_bfloat16* __restrict__ prefsT,
    const __hip_bfloat16* __restrict__ W2,
    const float* __restrict__ bias,
    const __hip_bfloat16* __restrict__ Wh3,
    __hip_bfloat16* __restrict__ X0,
    __hip_bfloat16* __restrict__ X1,
    float* __restrict__ cbuf,
    float* __restrict__ s2part,
    int* arrive, int* release_,
    float* __restrict__ out_iw,
    float* __restrict__ out_ie)
{
    __shared__ float2 s2w[4][NT];            // (s2, wattn) per group
    __shared__ float  s2red[4][4][NT];
    __shared__ float  red_m[4][4], red_s[4][4];
    __shared__ float  bh_s[NT], wfsl_s[NT], wattn_s[NT];
    __shared__ float  battn_s;
    __shared__ float  bias_s[4][16];
    __shared__ float  gates_lds[4][64][17];  // padded: bank-spread
    __shared__ __hip_bfloat16 hcmini[64][40]; // padded to 80B rows (16B aligned)

    int tid = threadIdx.x;
    int blk = blockIdx.x;

    // phase A ids
    int g     = tid >> 8;      // batch group 0..3
    int it    = tid & 255;     // i index
    int b     = blk*4 + g;
    int gw    = it >> 6;       // wave-in-group 0..3
    int lane6 = it & 63;

    // phase B ids
    int wv   = tid >> 6, lane = tid & 63;
    int msub = wv & 3, q = wv >> 2;
    int mt   = blk >> 4, jt = blk & 15;
    int lm   = lane & 15, lk = (lane >> 4) * 8;
    int mloc = tid >> 4, jl = tid & 15;      // pointwise mapping

    // stage loop-invariant constants
    if (tid < NT){
        bh_s[tid]    = bh[tid];
        wfsl_s[tid]  = Wfs[TM1*NT + tid];
        wattn_s[tid] = Wattn[tid];
        bias_s[tid >> 4][tid & 15] = bias[(tid >> 4)*256 + jt*16 + (tid & 15)];
    }
    if (tid == 64) battn_s = battn[0];
    __syncthreads();

    int gen = 0;

    for (int t = 0; t < TM1; ++t){
        __hip_bfloat16* Xc = (t & 1) ? X1 : X0;
        __hip_bfloat16* Xn = (t & 1) ? X0 : X1;

        // ------------------ Phase A: attention for batch b ------------------
        {
            const bf16x8* pfT = (const bf16x8*)(prefsT + ((long)b*NI + it)*NT);
            bf16x8 pf[8];
            #pragma unroll
            for (int o = 0; o < 8; ++o) pf[o] = pfT[o];

            // distributed s2part reduce: this wave handles jt' in {gw+4q}
            {
                float acc4 = 0.f;
                #pragma unroll
                for (int qq = 0; qq < 4; ++qq)
                    acc4 += s2part[((long)(gw + 4*qq)*NB + b)*NT + lane6];
                s2red[g][gw][lane6] = acc4;
            }
            __syncthreads();
            if (it < NT){
                float y = yhist[b*TM1 + t];
                float s2v = s2red[g][0][it] + s2red[g][1][it]
                          + s2red[g][2][it] + s2red[g][3][it]
                          + bh_s[it] + y * wfsl_s[it];
                s2w[g][it] = make_float2(s2v, wattn_s[it]);
            }
            __syncthreads();

            float acc = 0.f;
            #pragma unroll
            for (int o = 0; o < 8; ++o){
                #pragma unroll
                for (int j = 0; j < 8; ++j){
                    float2 sw = s2w[g][o*8 + j];
                    float x = sw.x + bf16s_to_f(pf[o][j]);
                    acc = fmaf(fast_tanh(x), sw.y, acc);
                }
            }
            float attn = acc + battn_s;

            // softmax over the group's 256 threads
            float mx = attn;
            #pragma unroll
            for (int o = 32; o > 0; o >>= 1) mx = fmaxf(mx, __shfl_xor(mx, o, 64));
            if (lane6 == 0) red_m[g][gw] = mx;
            __syncthreads();
            mx = fmaxf(fmaxf(red_m[g][0], red_m[g][1]),
                       fmaxf(red_m[g][2], red_m[g][3]));
            float p = fast_exp2((attn - mx) * 1.4426950408889634f);
            float ss = p;
            #pragma unroll
            for (int o = 32; o > 0; o >>= 1) ss += __shfl_xor(ss, o, 64);
            if (lane6 == 0) red_s[g][gw] = ss;
            __syncthreads();
            ss = red_s[g][0] + red_s[g][1] + red_s[g][2] + red_s[g][3];
            float a = p * fast_rcp(ss);

            float w = a * FS[((long)b*TM1 + t)*NI + it];
            Xc[b*512 + it] = __float2bfloat16(w);
            out_iw[((long)b*TM1 + t)*NI + it] = w;
        }

        gridbar(arrive, release_, ++gen);

        // ------------------ Phase B: gates + pointwise + mini-GEMM ----------
        {
            int m0 = mt*64 + msub*16;
            const __hip_bfloat16* xrow = Xc + (long)(m0 + lm) * 512;
            const __hip_bfloat16* wrow = W2 + (long)(q*256 + jt*16 + lm) * 512;
            f32x4 acc = {};
            #pragma unroll
            for (int kc = 0; kc < 16; ++kc){
                bf16x8 afrag = *(const bf16x8*)(xrow + kc*32 + lk);
                bf16x8 bfrag = *(const bf16x8*)(wrow + kc*32 + lk);
                acc = __builtin_amdgcn_mfma_f32_16x16x32_bf16(afrag, bfrag, acc, 0, 0, 0);
            }
            {
                int row0 = msub*16 + (lane >> 4)*4;
                #pragma unroll
                for (int r = 0; r < 4; ++r)
                    gates_lds[q][row0 + r][lm] = acc[r];
            }
            __syncthreads();
            {
                int m = mt*64 + mloc, j = jt*16 + jl;
                float ig = gates_lds[0][mloc][jl] + bias_s[0][jl];
                float fg = gates_lds[1][mloc][jl] + bias_s[1][jl];
                float gg = gates_lds[2][mloc][jl] + bias_s[2][jl];
                float og = gates_lds[3][mloc][jl] + bias_s[3][jl];
                float cold = cbuf[m*NH + j];
                float cn = fast_sigmoid(fg) * cold + fast_sigmoid(ig) * fast_tanh(gg);
                float hn = fast_sigmoid(og) * fast_tanh(cn);
                cbuf[m*NH + j] = cn;
                Xn[(long)m*512 + 256 + j] = __float2bfloat16(hn);
                out_ie[((long)m*TM1 + t)*NH + j] = hn;
                hcmini[mloc][jl]      = __float2bfloat16(hn);
                hcmini[mloc][16 + jl] = __float2bfloat16(cn);
            }
            __syncthreads();
            {
                bf16x8 af = *(const bf16x8*)&hcmini[msub*16 + lm][lk];
                bf16x8 bfrag = *(const bf16x8*)(Wh3 + ((long)jt*64 + q*16 + lm)*32 + lk);
                f32x4 sacc = {};
                sacc = __builtin_amdgcn_mfma_f32_16x16x32_bf16(af, bfrag, sacc, 0, 0, 0);
                int u = q*16 + lm;
                #pragma unroll
                for (int r = 0; r < 4; ++r){
                    int m = mt*64 + msub*16 + (lane >> 4)*4 + r;
                    s2part[((long)jt*NB + m)*NT + u] = sacc[r];
                }
            }
        }

        if (t < TM1 - 1) gridbar(arrive, release_, ++gen);
    }
}

// ---------------------------------------------------------------------------
extern "C" void kernel_launch(void* const* d_in, const int* in_sizes, int n_in,
                              void* d_out, int out_size, void* d_ws, size_t ws_size,
                              hipStream_t stream)
{
    const float* FS    = (const float*)d_in[0];
    const float* yh    = (const float*)d_in[1];
    const float* Wh    = (const float*)d_in[2];
    const float* bh    = (const float*)d_in[3];
    const float* Wfs   = (const float*)d_in[4];
    const float* bfs   = (const float*)d_in[5];
    const float* Wattn = (const float*)d_in[6];
    const float* battn = (const float*)d_in[7];
    const float* Wih   = (const float*)d_in[8];
    const float* Whh   = (const float*)d_in[9];
    const float* bih   = (const float*)d_in[10];
    const float* bhh   = (const float*)d_in[11];

    char* ws = (char*)d_ws;
    const size_t MB = 1048576;
    // layout after prefsT(32MB):
    //   X0 1MB | c 1MB | s2part 4MB | barrier 4KB | (pad to 7MB) X1 1MB |
    //   W2 1MB | bias 4KB | Wh3 64KB
    __hip_bfloat16* prefsT = (__hip_bfloat16*)ws;
    size_t off = (size_t)NB * NI * NT * sizeof(__hip_bfloat16);   // 32 MB
    __hip_bfloat16* X0  = (__hip_bfloat16*)(ws + off);
    float* cbuf         = (float*)(ws + off + 1*MB);
    float* s2part       = (float*)(ws + off + 2*MB);
    int*   arrive       = (int*)(ws + off + 6*MB);
    int*   release_     = (int*)(ws + off + 6*MB + 2048);
    __hip_bfloat16* X1  = (__hip_bfloat16*)(ws + off + 7*MB);
    __hip_bfloat16* W2  = (__hip_bfloat16*)(ws + off + 8*MB);
    float* bias         = (float*)(ws + off + 9*MB);
    __hip_bfloat16* Wh3 = (__hip_bfloat16*)(ws + off + 9*MB + 4096);

    float* out_iw = (float*)d_out;                     // [B][63][I] f32
    float* out_ie = out_iw + (size_t)NB * TM1 * NI;    // [B][63][H] f32

    // zero X0 (h-half t=0) + c + s2part + barrier slots: contiguous 6MB+4KB
    hipMemsetAsync(ws + off, 0, 6*MB + 4096, stream);

    prep_w2<<<1152, 256, 0, stream>>>(Wih, Whh, bih, bhh, Wh, W2, bias, Wh3);
    prefs_kernel<<<NB, 256, 0, stream>>>(FS, Wfs, bfs, prefsT);

    void* args[] = {
        (void*)&FS, (void*)&yh, (void*)&bh, (void*)&Wfs, (void*)&Wattn,
        (void*)&battn, (void*)&prefsT, (void*)&W2, (void*)&bias, (void*)&Wh3,
        (void*)&X0, (void*)&X1, (void*)&cbuf, (void*)&s2part,
        (void*)&arrive, (void*)&release_, (void*)&out_iw, (void*)&out_ie
    };
    hipLaunchCooperativeKernel(reinterpret_cast<void*>(persist_kernel),
                               dim3(GRID_BLOCKS), dim3(BLOCK_THREADS),
                               args, 0, stream);
}

// Round 3
// 5309.145 us; speedup vs baseline: 1.3014x; 1.3014x over previous
//
#include <hip/hip_runtime.h>
#include <hip/hip_bf16.h>

// Problem dims (fixed)
#define NB 1024   // batch
#define NI 256    // input size
#define NH 256    // hidden
#define NT 64     // window T
#define TM1 63    // T-1 steps

typedef short bf16x8 __attribute__((ext_vector_type(8)));
typedef float f32x4 __attribute__((ext_vector_type(4)));

__device__ __forceinline__ float bf16s_to_f(short s){
    unsigned u = ((unsigned)(unsigned short)s) << 16;
    return __builtin_bit_cast(float, u);
}
__device__ __forceinline__ unsigned short f_to_bf16s(float f){
    __hip_bfloat16 h = __float2bfloat16(f);
    return *(unsigned short*)&h;
}
__device__ __forceinline__ unsigned pack_bf16(float lo, float hi){
    return (unsigned)f_to_bf16s(lo) | ((unsigned)f_to_bf16s(hi) << 16);
}

__device__ __forceinline__ float fast_exp2(float x){ return __builtin_amdgcn_exp2f(x); }
__device__ __forceinline__ float fast_rcp(float x){ return __builtin_amdgcn_rcpf(x); }
__device__ __forceinline__ float fast_tanh(float x){
    float e = fast_exp2(x * 2.8853900817779268f);   // 2*log2(e)
    return 1.f - 2.f * fast_rcp(e + 1.f);
}
__device__ __forceinline__ float fast_sigmoid(float x){
    return fast_rcp(1.f + fast_exp2(-1.4426950408889634f * x));
}

// ---------------------------------------------------------------------------
// One-time prep.
// blocks 0..1023:  W2[n][k] = bf16(k<256 ? Wih[n][k] : Whh[n][k-256]); bias=bih+bhh
// blocks 1024..1151: WhT[u][k] = bf16(Wh[k][u])  (bf16 transpose, k=0..511 = [h|c])
// ---------------------------------------------------------------------------
__global__ __launch_bounds__(256) void prep_w2(
    const float* __restrict__ Wih, const float* __restrict__ Whh,
    const float* __restrict__ bih, const float* __restrict__ bhh,
    const float* __restrict__ Wh,
    __hip_bfloat16* __restrict__ W2, float* __restrict__ bias,
    __hip_bfloat16* __restrict__ WhT)
{
    int tid = threadIdx.x;
    if (blockIdx.x < 1024){
        int n = blockIdx.x;
        W2[(long)n*512 + tid]       = __float2bfloat16(Wih[(long)n*256 + tid]);
        W2[(long)n*512 + 256 + tid] = __float2bfloat16(Whh[(long)n*256 + tid]);
        if (tid == 0) bias[n] = bih[n] + bhh[n];
    } else {
        int idx = (blockIdx.x - 1024) * 256 + tid;   // 0..32767
        int u = idx >> 9;          // 0..63
        int k = idx & 511;         // 0..511
        WhT[idx] = __float2bfloat16(Wh[k*NT + u]);   // WhT[u][k] = Wh[k][u]
    }
}

// ---------------------------------------------------------------------------
// prefsT[b][i][u] = b_fs[u] + sum_t FS[b][t][i]*W_fs[t][u]   (bf16, u-contig)
// (round-1 restructured version, unchanged)
// ---------------------------------------------------------------------------
__global__ __launch_bounds__(256) void prefs_kernel(
    const float* __restrict__ FS,    // [B][63][I] f32
    const float* __restrict__ Wfs,   // [64][64]   f32
    const float* __restrict__ bfs,   // [64]       f32
    __hip_bfloat16* __restrict__ prefsT)  // [B][I][64] bf16
{
    __shared__ float wfs_s[TM1][NT];
    int b = blockIdx.x, tid = threadIdx.x;
    for (int idx = tid; idx < TM1*NT; idx += 256)
        wfs_s[idx >> 6][idx & 63] = Wfs[idx];
    __syncthreads();

    const float* fsp = FS + (long)b*TM1*NI + tid;

    f32x4 acc[16];
    #pragma unroll
    for (int g = 0; g < 16; ++g) acc[g] = *(const f32x4*)(bfs + g*4);

    #pragma unroll 4
    for (int t = 0; t < TM1; ++t){
        float fs = fsp[(long)t*NI];
        #pragma unroll
        for (int g = 0; g < 16; ++g){
            f32x4 w4 = *(const f32x4*)&wfs_s[t][g*4];
            acc[g] += fs * w4;
        }
    }

    uint4* dst = (uint4*)(prefsT + ((long)b*NI + tid)*NT);
    #pragma unroll
    for (int g = 0; g < 16; g += 2){
        uint4 v;
        v.x = pack_bf16(acc[g][0],   acc[g][1]);
        v.y = pack_bf16(acc[g][2],   acc[g][3]);
        v.z = pack_bf16(acc[g+1][0], acc[g+1][1]);
        v.w = pack_bf16(acc[g+1][2], acc[g+1][3]);
        dst[g >> 1] = v;
    }
}

// ---------------------------------------------------------------------------
// Batch-local recurrent kernel: 256 blocks x 256 threads, 4 batches/block.
// ALL state (h, c, s2, w_in) lives in LDS; no global sync, single launch.
// Per step:
//   S: s2 = [h|c] @ Wh  (MFMA m=16 (4 real rows), n=64, K=512)
//   A: attn tanh loop + softmax (exact round-1 math), w_in -> hcx LDS
//   B: gates = [w_in|h] @ W2^T (m=16(4), n=1024, K=512, W2 streamed from L2)
//      + LSTM pointwise (f32 c in LDS), h/c -> bf16 LDS for next step.
// MFMA 16x16x32 bf16; A: m=lane&15,k=(lane>>4)*8+j ; B: n=lane&15, same k ;
// C/D: col=lane&15, row=(lane>>4)*4+reg   [learn_hip m89-verified]
// ---------------------------------------------------------------------------
__global__ __launch_bounds__(256, 1) void recurrent_kernel(
    const float* __restrict__ FS,       // [B][63][I]
    const float* __restrict__ yhist,    // [B][63]
    const float* __restrict__ bh,       // [64]
    const float* __restrict__ Wfs,      // [64][64] (last row used)
    const float* __restrict__ Wattn,    // [64]
    const float* __restrict__ battn,    // [1]
    const __hip_bfloat16* __restrict__ prefsT,  // [B][I][64]
    const __hip_bfloat16* __restrict__ W2,      // [1024][512]
    const float* __restrict__ bias,             // [1024]
    const __hip_bfloat16* __restrict__ WhT,     // [64][512]
    float* __restrict__ out_iw,         // [B][63][I] f32
    float* __restrict__ out_ie)         // [B][63][H] f32
{
    __shared__ __align__(16) __hip_bfloat16 hcx[4][520];  // [w_in(256) | h(256)]
    __shared__ __align__(16) __hip_bfloat16 hc2[4][520];  // [h(256) | c(256)]
    __shared__ __align__(16) float c_s[4][264];
    __shared__ __align__(16) float gates_s[4][1032];
    __shared__ __align__(16) float s2_s[4][72];
    __shared__ __align__(16) float bias_s[1024];
    __shared__ __align__(16) float bh_s[NT], wfsl_s[NT], wattn_s[NT];
    __shared__ float yv[4];
    __shared__ float redm[4][4], reds[4][4];
    __shared__ float battn_s;

    int tid  = threadIdx.x;
    int b0   = blockIdx.x * 4;
    int wave = tid >> 6, lane = tid & 63;
    int lm   = lane & 15, lk = (lane >> 4) * 8;
    int brow = lm & 3;                      // batch row for MFMA A (rows 4-15 dup)

    // ---- one-time staging ----
    for (int idx = tid; idx < 1024; idx += 256) bias_s[idx] = bias[idx];
    if (tid < NT){
        bh_s[tid]    = bh[tid];
        wfsl_s[tid]  = Wfs[TM1*NT + tid];
        wattn_s[tid] = Wattn[tid];
    }
    if (tid == 64) battn_s = battn[0];
    {   // zero state
        int b = tid >> 6, j = tid & 63;
        #pragma unroll
        for (int p = 0; p < 4; ++p){
            int jj = j + p*64;
            hcx[b][256+jj] = __float2bfloat16(0.f);
            hc2[b][jj]     = __float2bfloat16(0.f);
            hc2[b][256+jj] = __float2bfloat16(0.f);
            c_s[b][jj]     = 0.f;
        }
    }
    __syncthreads();

    for (int t = 0; t < TM1; ++t){
        if (tid < 4) yv[tid] = yhist[(b0 + tid)*TM1 + t];

        // ---------------- Phase S: s2 = hc @ Wh ----------------
        {
            int u0 = wave * 16;
            const __hip_bfloat16* wrow = WhT + (long)(u0 + lm)*512 + lk;
            f32x4 sacc = {};
            #pragma unroll
            for (int kc = 0; kc < 16; ++kc){
                bf16x8 af = *(const bf16x8*)&hc2[brow][kc*32 + lk];
                bf16x8 bf = *(const bf16x8*)(wrow + kc*32);
                sacc = __builtin_amdgcn_mfma_f32_16x16x32_bf16(af, bf, sacc, 0, 0, 0);
            }
            if (lane < 16){
                #pragma unroll
                for (int r = 0; r < 4; ++r) s2_s[r][u0 + lane] = sacc[r];
            }
        }
        __syncthreads();
        {   // finalize: + bh + y*wfs_last   (256 threads cover 4x64)
            int bb = wave, u = lane;
            s2_s[bb][u] += bh_s[u] + yv[bb] * wfsl_s[u];
        }
        __syncthreads();

        // ---------------- Phase A: attention ----------------
        float attnv[4];
        #pragma unroll
        for (int bb = 0; bb < 4; ++bb){
            const bf16x8* pfT = (const bf16x8*)(prefsT + ((long)(b0+bb)*NI + tid)*NT);
            bf16x8 pf[8];
            #pragma unroll
            for (int o = 0; o < 8; ++o) pf[o] = pfT[o];
            float acc0 = 0.f, acc1 = 0.f;
            #pragma unroll
            for (int o = 0; o < 8; ++o){
                f32x4 sa = *(const f32x4*)&s2_s[bb][o*8];
                f32x4 sb = *(const f32x4*)&s2_s[bb][o*8 + 4];
                f32x4 wa = *(const f32x4*)&wattn_s[o*8];
                f32x4 wb = *(const f32x4*)&wattn_s[o*8 + 4];
                #pragma unroll
                for (int j = 0; j < 4; ++j){
                    acc0 = fmaf(fast_tanh(sa[j] + bf16s_to_f(pf[o][j])),   wa[j], acc0);
                    acc1 = fmaf(fast_tanh(sb[j] + bf16s_to_f(pf[o][j+4])), wb[j], acc1);
                }
            }
            attnv[bb] = acc0 + acc1 + battn_s;
        }

        // softmax over 256 i (4 batches in parallel)
        #pragma unroll
        for (int bb = 0; bb < 4; ++bb){
            float m = attnv[bb];
            #pragma unroll
            for (int o = 32; o > 0; o >>= 1) m = fmaxf(m, __shfl_xor(m, o, 64));
            if (lane == 0) redm[bb][wave] = m;
        }
        __syncthreads();
        float fsv[4], pv[4];
        #pragma unroll
        for (int bb = 0; bb < 4; ++bb)
            fsv[bb] = FS[((long)(b0+bb)*TM1 + t)*NI + tid];
        #pragma unroll
        for (int bb = 0; bb < 4; ++bb){
            float m = fmaxf(fmaxf(redm[bb][0], redm[bb][1]),
                            fmaxf(redm[bb][2], redm[bb][3]));
            float p = fast_exp2((attnv[bb] - m) * 1.4426950408889634f);
            pv[bb] = p;
            float ss = p;
            #pragma unroll
            for (int o = 32; o > 0; o >>= 1) ss += __shfl_xor(ss, o, 64);
            if (lane == 0) reds[bb][wave] = ss;
        }
        __syncthreads();
        #pragma unroll
        for (int bb = 0; bb < 4; ++bb){
            float ss = reds[bb][0] + reds[bb][1] + reds[bb][2] + reds[bb][3];
            float w = pv[bb] * fast_rcp(ss) * fsv[bb];
            hcx[bb][tid] = __float2bfloat16(w);
            out_iw[((long)(b0+bb)*TM1 + t)*NI + tid] = w;
        }
        __syncthreads();

        // ---------------- Phase B: gates GEMM + pointwise ----------------
        {
            bf16x8 Af[16];
            #pragma unroll
            for (int kc = 0; kc < 16; ++kc)
                Af[kc] = *(const bf16x8*)&hcx[brow][kc*32 + lk];

            #pragma unroll 2
            for (int d = 0; d < 16; ++d){
                int n0 = wave*256 + d*16;
                const __hip_bfloat16* wp = W2 + (long)(n0 + lm)*512 + lk;
                f32x4 acc = {};
                #pragma unroll
                for (int kc = 0; kc < 16; ++kc){
                    bf16x8 bfrag = *(const bf16x8*)(wp + kc*32);
                    acc = __builtin_amdgcn_mfma_f32_16x16x32_bf16(Af[kc], bfrag, acc, 0, 0, 0);
                }
                if (lane < 16){
                    #pragma unroll
                    for (int r = 0; r < 4; ++r) gates_s[r][n0 + lane] = acc[r];
                }
            }
        }
        __syncthreads();
        {   // pointwise: wave handles its batch; 4 passes over j
            int bb = wave;
            #pragma unroll
            for (int p = 0; p < 4; ++p){
                int j = lane + p*64;
                float ig = gates_s[bb][j]       + bias_s[j];
                float fg = gates_s[bb][256 + j] + bias_s[256 + j];
                float gg = gates_s[bb][512 + j] + bias_s[512 + j];
                float og = gates_s[bb][768 + j] + bias_s[768 + j];
                float cold = c_s[bb][j];
                float cn = fast_sigmoid(fg)*cold + fast_sigmoid(ig)*fast_tanh(gg);
                float hn = fast_sigmoid(og)*fast_tanh(cn);
                c_s[bb][j]     = cn;
                hcx[bb][256+j] = __float2bfloat16(hn);
                hc2[bb][j]     = __float2bfloat16(hn);
                hc2[bb][256+j] = __float2bfloat16(cn);
                out_ie[((long)(b0+bb)*TM1 + t)*NH + j] = hn;
            }
        }
        __syncthreads();
    }
}

// ---------------------------------------------------------------------------
extern "C" void kernel_launch(void* const* d_in, const int* in_sizes, int n_in,
                              void* d_out, int out_size, void* d_ws, size_t ws_size,
                              hipStream_t stream)
{
    const float* FS    = (const float*)d_in[0];
    const float* yh    = (const float*)d_in[1];
    const float* Wh    = (const float*)d_in[2];
    const float* bh    = (const float*)d_in[3];
    const float* Wfs   = (const float*)d_in[4];
    const float* bfs   = (const float*)d_in[5];
    const float* Wattn = (const float*)d_in[6];
    const float* battn = (const float*)d_in[7];
    const float* Wih   = (const float*)d_in[8];
    const float* Whh   = (const float*)d_in[9];
    const float* bih   = (const float*)d_in[10];
    const float* bhh   = (const float*)d_in[11];

    char* ws = (char*)d_ws;
    const size_t MB = 1048576;
    // layout: prefsT 32MB | W2 1MB | bias 4KB | WhT 64KB
    __hip_bfloat16* prefsT = (__hip_bfloat16*)ws;
    size_t off = (size_t)NB * NI * NT * sizeof(__hip_bfloat16);   // 32 MB
    __hip_bfloat16* W2  = (__hip_bfloat16*)(ws + off);
    float* bias         = (float*)(ws + off + 1*MB);
    __hip_bfloat16* WhT = (__hip_bfloat16*)(ws + off + 1*MB + 4096);

    float* out_iw = (float*)d_out;                     // [B][63][I] f32
    float* out_ie = out_iw + (size_t)NB * TM1 * NI;    // [B][63][H] f32

    prep_w2<<<1152, 256, 0, stream>>>(Wih, Whh, bih, bhh, Wh, W2, bias, WhT);
    prefs_kernel<<<NB, 256, 0, stream>>>(FS, Wfs, bfs, prefsT);
    recurrent_kernel<<<256, 256, 0, stream>>>(FS, yh, bh, Wfs, Wattn, battn,
                                              prefsT, W2, bias, WhT,
                                              out_iw, out_ie);
}

// Round 5
// 2556.333 us; speedup vs baseline: 2.7028x; 2.0769x over previous
//
#include <hip/hip_runtime.h>
#include <hip/hip_bf16.h>

// Problem dims (fixed)
#define NB 1024   // batch
#define NI 256    // input size
#define NH 256    // hidden
#define NT 64     // window T
#define TM1 63    // T-1 steps

typedef short bf16x8 __attribute__((ext_vector_type(8)));
typedef float f32x4 __attribute__((ext_vector_type(4)));

__device__ __forceinline__ float bf16s_to_f(short s){
    unsigned u = ((unsigned)(unsigned short)s) << 16;
    return __builtin_bit_cast(float, u);
}
__device__ __forceinline__ unsigned short f_to_bf16s(float f){
    __hip_bfloat16 h = __float2bfloat16(f);
    return *(unsigned short*)&h;
}
__device__ __forceinline__ unsigned pack_bf16(float lo, float hi){
    return (unsigned)f_to_bf16s(lo) | ((unsigned)f_to_bf16s(hi) << 16);
}

__device__ __forceinline__ float fast_exp2(float x){ return __builtin_amdgcn_exp2f(x); }
__device__ __forceinline__ float fast_rcp(float x){ return __builtin_amdgcn_rcpf(x); }
__device__ __forceinline__ float fast_tanh(float x){
    float e = fast_exp2(x * 2.8853900817779268f);   // 2*log2(e)
    return 1.f - 2.f * fast_rcp(e + 1.f);
}
__device__ __forceinline__ float fast_sigmoid(float x){
    return fast_rcp(1.f + fast_exp2(-1.4426950408889634f * x));
}

// ---------------------------------------------------------------------------
// One-time prep.
// blocks 0..1023:  W2[n][k] = bf16(k<256 ? Wih[n][k] : Whh[n][k-256]); bias=bih+bhh
// blocks 1024..1151: WhT[u][k] = bf16(Wh[k][u])  (bf16 transpose, k=0..511 = [h|c])
// ---------------------------------------------------------------------------
__global__ __launch_bounds__(256) void prep_w2(
    const float* __restrict__ Wih, const float* __restrict__ Whh,
    const float* __restrict__ bih, const float* __restrict__ bhh,
    const float* __restrict__ Wh,
    __hip_bfloat16* __restrict__ W2, float* __restrict__ bias,
    __hip_bfloat16* __restrict__ WhT)
{
    int tid = threadIdx.x;
    if (blockIdx.x < 1024){
        int n = blockIdx.x;
        W2[(long)n*512 + tid]       = __float2bfloat16(Wih[(long)n*256 + tid]);
        W2[(long)n*512 + 256 + tid] = __float2bfloat16(Whh[(long)n*256 + tid]);
        if (tid == 0) bias[n] = bih[n] + bhh[n];
    } else {
        int idx = (blockIdx.x - 1024) * 256 + tid;   // 0..32767
        int u = idx >> 9;          // 0..63
        int k = idx & 511;         // 0..511
        WhT[idx] = __float2bfloat16(Wh[k*NT + u]);   // WhT[u][k] = Wh[k][u]
    }
}

// ---------------------------------------------------------------------------
// prefsT[b][i][u] = b_fs[u] + sum_t FS[b][t][i]*W_fs[t][u]   (bf16, u-contig)
// ---------------------------------------------------------------------------
__global__ __launch_bounds__(256) void prefs_kernel(
    const float* __restrict__ FS,    // [B][63][I] f32
    const float* __restrict__ Wfs,   // [64][64]   f32
    const float* __restrict__ bfs,   // [64]       f32
    __hip_bfloat16* __restrict__ prefsT)  // [B][I][64] bf16
{
    __shared__ float wfs_s[TM1][NT];
    int b = blockIdx.x, tid = threadIdx.x;
    for (int idx = tid; idx < TM1*NT; idx += 256)
        wfs_s[idx >> 6][idx & 63] = Wfs[idx];
    __syncthreads();

    const float* fsp = FS + (long)b*TM1*NI + tid;

    f32x4 acc[16];
    #pragma unroll
    for (int g = 0; g < 16; ++g) acc[g] = *(const f32x4*)(bfs + g*4);

    #pragma unroll 4
    for (int t = 0; t < TM1; ++t){
        float fs = fsp[(long)t*NI];
        #pragma unroll
        for (int g = 0; g < 16; ++g){
            f32x4 w4 = *(const f32x4*)&wfs_s[t][g*4];
            acc[g] += fs * w4;
        }
    }

    uint4* dst = (uint4*)(prefsT + ((long)b*NI + tid)*NT);
    #pragma unroll
    for (int g = 0; g < 16; g += 2){
        uint4 v;
        v.x = pack_bf16(acc[g][0],   acc[g][1]);
        v.y = pack_bf16(acc[g][2],   acc[g][3]);
        v.z = pack_bf16(acc[g+1][0], acc[g+1][1]);
        v.w = pack_bf16(acc[g+1][2], acc[g+1][3]);
        dst[g >> 1] = v;
    }
}

// ---------------------------------------------------------------------------
// Batch-local recurrent kernel: 256 blocks x 256 threads, 4 batches/block.
// prefsT (t-invariant, 128 KB/block) staged in LDS ONCE -> zero per-step
// global traffic except W2 (L2-resident) + FS (4 KB nt) + output stores (nt).
// Per step:
//   S: s2 = [h|c] @ WhT    (MFMA m=16(4 real), n=64, K=512)
//   A: tanh/softmax attention from LDS pf + s2; w_in -> hcq LDS
//   B: gates = [w_in|h] @ W2^T (n=1024, K=512, W2 from L2) + LSTM pointwise
// MFMA 16x16x32 bf16; A: m=lane&15,k=(lane>>4)*8+j ; B: n=lane&15, same k ;
// C/D: col=lane&15, row=(lane>>4)*4+reg   [learn_hip m89-verified]
// ---------------------------------------------------------------------------
__global__ __launch_bounds__(256, 1) void recurrent_kernel(
    const float* __restrict__ FS,       // [B][63][I]
    const float* __restrict__ yhist,    // [B][63]
    const float* __restrict__ bh,       // [64]
    const float* __restrict__ Wfs,      // [64][64] (last row used)
    const float* __restrict__ Wattn,    // [64]
    const float* __restrict__ battn,    // [1]
    const __hip_bfloat16* __restrict__ prefsT,  // [B][I][64]
    const __hip_bfloat16* __restrict__ W2,      // [1024][512]
    const float* __restrict__ bias,             // [1024]
    const __hip_bfloat16* __restrict__ WhT,     // [64][512]
    float* __restrict__ out_iw,         // [B][63][I] f32
    float* __restrict__ out_ie)         // [B][63][H] f32
{
    __shared__ __align__(16) __hip_bfloat16 pf_lds[8][4][256][8];  // 128 KB, t-invariant
    __shared__ __align__(16) __hip_bfloat16 hcq[4][776];  // [w_in(256)|h(256)|c(256)]+pad
    __shared__ __align__(16) float c_s[4][260];
    __shared__ __align__(16) float gates_s[4][1028];
    __shared__ __align__(16) float s2_s[4][68];
    __shared__ __align__(16) float bh_s[NT], wfsl_s[NT], wattn_s[NT];
    __shared__ float yh_s[4][NT];
    __shared__ float redm[4][4], reds[4][4];
    __shared__ float battn_s;

    int tid  = threadIdx.x;
    int b0   = blockIdx.x * 4;
    int wave = tid >> 6, lane = tid & 63;
    int lm   = lane & 15, lk = (lane >> 4) * 8;
    int brow = lm & 3;                      // batch row for MFMA A (rows 4-15 dup)

    // ---- one-time staging ----
    // prefsT -> LDS (t-invariant): [o][bb][i][8], lane-contiguous reads
    #pragma unroll
    for (int bb = 0; bb < 4; ++bb){
        const bf16x8* src = (const bf16x8*)(prefsT + ((long)(b0+bb)*NI + tid)*NT);
        #pragma unroll
        for (int o = 0; o < 8; ++o)
            *(bf16x8*)&pf_lds[o][bb][tid][0] = src[o];
    }
    {   // yhist row per batch, once
        int bb = tid >> 6, tt = tid & 63;
        if (tt < TM1) yh_s[bb][tt] = yhist[(b0 + bb)*TM1 + tt];
    }
    if (tid < NT){
        bh_s[tid]    = bh[tid];
        wfsl_s[tid]  = Wfs[TM1*NT + tid];
        wattn_s[tid] = Wattn[tid];
    }
    if (tid == 64) battn_s = battn[0];
    // bias in per-thread regs: br[q][p] = bias[q*256 + p*64 + lane]
    float br[4][4];
    #pragma unroll
    for (int q = 0; q < 4; ++q)
        #pragma unroll
        for (int p = 0; p < 4; ++p)
            br[q][p] = bias[q*256 + p*64 + lane];
    {   // zero state: h, c halves of hcq + f32 c
        int bb = tid >> 6, j = tid & 63;
        #pragma unroll
        for (int p = 0; p < 4; ++p){
            int jj = j + p*64;
            hcq[bb][256 + jj] = __float2bfloat16(0.f);
            hcq[bb][512 + jj] = __float2bfloat16(0.f);
            c_s[bb][jj]       = 0.f;
        }
    }
    __syncthreads();

    for (int t = 0; t < TM1; ++t){
        // FS prefetch (used at end of phase A; latency hidden under S+A)
        float fsv[4];
        #pragma unroll
        for (int bb = 0; bb < 4; ++bb)
            fsv[bb] = __builtin_nontemporal_load(
                FS + ((long)(b0+bb)*TM1 + t)*NI + tid);

        // ---------------- Phase S: s2 = [h|c] @ WhT ----------------
        {
            int u0 = wave * 16;
            const __hip_bfloat16* wrow = WhT + (long)(u0 + lm)*512 + lk;
            f32x4 sacc = {};
            #pragma unroll
            for (int kc = 0; kc < 16; ++kc){
                bf16x8 af = *(const bf16x8*)&hcq[brow][256 + kc*32 + lk];
                bf16x8 bf = *(const bf16x8*)(wrow + kc*32);
                sacc = __builtin_amdgcn_mfma_f32_16x16x32_bf16(af, bf, sacc, 0, 0, 0);
            }
            if (lane < 16){
                #pragma unroll
                for (int r = 0; r < 4; ++r) s2_s[r][u0 + lane] = sacc[r];
            }
        }
        __syncthreads();
        {   // finalize: + bh + y*wfs_last
            int bb = wave, u = lane;
            s2_s[bb][u] += bh_s[u] + yh_s[bb][t] * wfsl_s[u];
        }
        __syncthreads();

        // ---------------- Phase A: attention ----------------
        float attnv[4];
        #pragma unroll
        for (int bb = 0; bb < 4; ++bb){
            float acc0 = 0.f, acc1 = 0.f;
            #pragma unroll
            for (int o = 0; o < 8; ++o){
                bf16x8 pf = *(const bf16x8*)&pf_lds[o][bb][tid][0];
                f32x4 sa = *(const f32x4*)&s2_s[bb][o*8];
                f32x4 sb = *(const f32x4*)&s2_s[bb][o*8 + 4];
                f32x4 wa = *(const f32x4*)&wattn_s[o*8];
                f32x4 wb = *(const f32x4*)&wattn_s[o*8 + 4];
                #pragma unroll
                for (int j = 0; j < 4; ++j){
                    acc0 = fmaf(fast_tanh(sa[j] + bf16s_to_f(pf[j])),   wa[j], acc0);
                    acc1 = fmaf(fast_tanh(sb[j] + bf16s_to_f(pf[j+4])), wb[j], acc1);
                }
            }
            attnv[bb] = acc0 + acc1 + battn_s;
        }

        // softmax over 256 i (4 batches in parallel)
        #pragma unroll
        for (int bb = 0; bb < 4; ++bb){
            float m = attnv[bb];
            #pragma unroll
            for (int o = 32; o > 0; o >>= 1) m = fmaxf(m, __shfl_xor(m, o, 64));
            if (lane == 0) redm[bb][wave] = m;
        }
        __syncthreads();
        float pv[4];
        #pragma unroll
        for (int bb = 0; bb < 4; ++bb){
            float m = fmaxf(fmaxf(redm[bb][0], redm[bb][1]),
                            fmaxf(redm[bb][2], redm[bb][3]));
            float p = fast_exp2((attnv[bb] - m) * 1.4426950408889634f);
            pv[bb] = p;
            float ss = p;
            #pragma unroll
            for (int o = 32; o > 0; o >>= 1) ss += __shfl_xor(ss, o, 64);
            if (lane == 0) reds[bb][wave] = ss;
        }
        __syncthreads();
        #pragma unroll
        for (int bb = 0; bb < 4; ++bb){
            float ss = reds[bb][0] + reds[bb][1] + reds[bb][2] + reds[bb][3];
            float w = pv[bb] * fast_rcp(ss) * fsv[bb];
            hcq[bb][tid] = __float2bfloat16(w);
            __builtin_nontemporal_store(w,
                out_iw + ((long)(b0+bb)*TM1 + t)*NI + tid);
        }
        __syncthreads();

        // ---------------- Phase B: gates GEMM + pointwise ----------------
        {
            bf16x8 Af[16];
            #pragma unroll
            for (int kc = 0; kc < 16; ++kc)
                Af[kc] = *(const bf16x8*)&hcq[brow][kc*32 + lk];

            #pragma unroll 2
            for (int d = 0; d < 16; ++d){
                int n0 = wave*256 + d*16;
                const __hip_bfloat16* wp = W2 + (long)(n0 + lm)*512 + lk;
                f32x4 acc = {};
                #pragma unroll
                for (int kc = 0; kc < 16; ++kc){
                    bf16x8 bfrag = *(const bf16x8*)(wp + kc*32);
                    acc = __builtin_amdgcn_mfma_f32_16x16x32_bf16(Af[kc], bfrag, acc, 0, 0, 0);
                }
                if (lane < 16){
                    #pragma unroll
                    for (int r = 0; r < 4; ++r) gates_s[r][n0 + lane] = acc[r];
                }
            }
        }
        __syncthreads();
        {   // pointwise: wave handles its batch; 4 passes over j
            int bb = wave;
            #pragma unroll
            for (int p = 0; p < 4; ++p){
                int j = lane + p*64;
                float ig = gates_s[bb][j]       + br[0][p];
                float fg = gates_s[bb][256 + j] + br[1][p];
                float gg = gates_s[bb][512 + j] + br[2][p];
                float og = gates_s[bb][768 + j] + br[3][p];
                float cold = c_s[bb][j];
                float cn = fast_sigmoid(fg)*cold + fast_sigmoid(ig)*fast_tanh(gg);
                float hn = fast_sigmoid(og)*fast_tanh(cn);
                c_s[bb][j]      = cn;
                hcq[bb][256+j]  = __float2bfloat16(hn);
                hcq[bb][512+j]  = __float2bfloat16(cn);
                __builtin_nontemporal_store(hn,
                    out_ie + ((long)(b0+bb)*TM1 + t)*NH + j);
            }
        }
        __syncthreads();
    }
}

// ---------------------------------------------------------------------------
extern "C" void kernel_launch(void* const* d_in, const int* in_sizes, int n_in,
                              void* d_out, int out_size, void* d_ws, size_t ws_size,
                              hipStream_t stream)
{
    const float* FS    = (const float*)d_in[0];
    const float* yh    = (const float*)d_in[1];
    const float* Wh    = (const float*)d_in[2];
    const float* bh    = (const float*)d_in[3];
    const float* Wfs   = (const float*)d_in[4];
    const float* bfs   = (const float*)d_in[5];
    const float* Wattn = (const float*)d_in[6];
    const float* battn = (const float*)d_in[7];
    const float* Wih   = (const float*)d_in[8];
    const float* Whh   = (const float*)d_in[9];
    const float* bih   = (const float*)d_in[10];
    const float* bhh   = (const float*)d_in[11];

    char* ws = (char*)d_ws;
    const size_t MB = 1048576;
    // layout: prefsT 32MB | W2 1MB | bias 4KB | WhT 64KB
    __hip_bfloat16* prefsT = (__hip_bfloat16*)ws;
    size_t off = (size_t)NB * NI * NT * sizeof(__hip_bfloat16);   // 32 MB
    __hip_bfloat16* W2  = (__hip_bfloat16*)(ws + off);
    float* bias         = (float*)(ws + off + 1*MB);
    __hip_bfloat16* WhT = (__hip_bfloat16*)(ws + off + 1*MB + 4096);

    float* out_iw = (float*)d_out;                     // [B][63][I] f32
    float* out_ie = out_iw + (size_t)NB * TM1 * NI;    // [B][63][H] f32

    prep_w2<<<1152, 256, 0, stream>>>(Wih, Whh, bih, bhh, Wh, W2, bias, WhT);
    prefs_kernel<<<NB, 256, 0, stream>>>(FS, Wfs, bfs, prefsT);
    recurrent_kernel<<<256, 256, 0, stream>>>(FS, yh, bh, Wfs, Wattn, battn,
                                              prefsT, W2, bias, WhT,
                                              out_iw, out_ie);
}